// Round 9
// baseline (571.599 us; speedup 1.0000x reference)
//
#include <hip/hip_runtime.h>
#include <stdint.h>

#define N_NODES 100000
#define N_EDGES 3200000
#define D_FEAT 256
#define CHUNK 8192
#define NBLK_E 391            // ceil(N_EDGES / CHUNK)
#define NBKT 391              // row >> 8 buckets (256 rows each)
#define EPB 2048              // edges histogrammed per gemm block (1563*2048 >= E)
#define CAP 9216              // LDS edge staging per spmm block (mean 8184, +11 sigma)

typedef __attribute__((ext_vector_type(8))) short short8;
typedef __attribute__((ext_vector_type(8))) ushort ushort8;
typedef __attribute__((ext_vector_type(4))) float float4v;

__device__ inline unsigned short f2bf(float f) {
    union { float f; unsigned u; } v; v.f = f;
    unsigned u = v.u;
    u += 0x7FFF + ((u >> 16) & 1);   // round-to-nearest-even
    return (unsigned short)(u >> 16);
}
__device__ inline float bf2f(unsigned short u) {
    union { unsigned u; float f; } v; v.u = (unsigned)u << 16;
    return v.f;
}

// ---- K1: W fp32 -> bf16, zero bucket totals ------------------------------
__global__ __launch_bounds__(256) void prep_kernel(const float* __restrict__ W,
                                                   ushort* __restrict__ Wbf,
                                                   int* __restrict__ tot) {
    int b = blockIdx.x;
    if (b < 256) {
        int i = b * 256 + threadIdx.x;           // 65536 W elements, exact
        Wbf[i] = f2bf(W[i]);
    } else {
        for (int i = threadIdx.x; i < NBKT; i += 256) tot[i] = 0;  // all 391
    }
}

// ---- K2: GEMM y = x @ W^T  + LDS-staged bucket histogram -----------------
// Hist: LDS atomics over the block's 2048-edge slice; 391 global adds at end
// (fire-and-forget, after the MFMA body -> no vmcnt pollution in the loop).
__global__ __launch_bounds__(256) void gemm_x_kernel(
        const float* __restrict__ x,      // [N][256] fp32
        const ushort* __restrict__ Wbf,   // [256][256] bf16, n-major
        const int* __restrict__ erow,
        int* __restrict__ tot,
        ushort* __restrict__ ybf) {       // [N][256] bf16
    __shared__ int hcnt[NBKT];
    for (int b = threadIdx.x; b < NBKT; b += 256) hcnt[b] = 0;
    __syncthreads();
    int eb = blockIdx.x * EPB;
    #pragma unroll
    for (int j = 0; j < EPB; j += 256) {
        int i = eb + j + threadIdx.x;
        if (i < N_EDGES) atomicAdd(&hcnt[erow[i] >> 8], 1);
    }

    int w    = threadIdx.x >> 6;
    int lane = threadIdx.x & 63;
    int quad = lane >> 4;
    int l16  = lane & 15;
    int rt   = blockIdx.x * 64;           // 1563 blocks

    float4v acc[4][4];
    #pragma unroll
    for (int mt = 0; mt < 4; ++mt)
        #pragma unroll
        for (int nt = 0; nt < 4; ++nt) acc[mt][nt] = (float4v){0.f, 0.f, 0.f, 0.f};

    #pragma unroll
    for (int k0 = 0; k0 < 256; k0 += 32) {
        short8 a[4], bf[4];
        #pragma unroll
        for (int mt = 0; mt < 4; ++mt) {
            int row = rt + mt * 16 + l16;
            if (row >= N_NODES) row = N_NODES - 1;   // clamp (tail block)
            const float4v* p = (const float4v*)&x[(size_t)row * 256 + k0 + quad * 8];
            float4v f0 = p[0], f1 = p[1];
            a[mt][0] = (short)f2bf(f0.x); a[mt][1] = (short)f2bf(f0.y);
            a[mt][2] = (short)f2bf(f0.z); a[mt][3] = (short)f2bf(f0.w);
            a[mt][4] = (short)f2bf(f1.x); a[mt][5] = (short)f2bf(f1.y);
            a[mt][6] = (short)f2bf(f1.z); a[mt][7] = (short)f2bf(f1.w);
        }
        #pragma unroll
        for (int nt = 0; nt < 4; ++nt) {
            int n = w * 64 + nt * 16 + l16;
            bf[nt] = *(const short8*)&Wbf[n * 256 + k0 + quad * 8];
        }
        #pragma unroll
        for (int mt = 0; mt < 4; ++mt)
            #pragma unroll
            for (int nt = 0; nt < 4; ++nt)
                acc[mt][nt] = __builtin_amdgcn_mfma_f32_16x16x32_bf16(a[mt], bf[nt], acc[mt][nt], 0, 0, 0);
    }
    #pragma unroll
    for (int mt = 0; mt < 4; ++mt)
        #pragma unroll
        for (int nt = 0; nt < 4; ++nt) {
            int n = w * 64 + nt * 16 + l16;
            #pragma unroll
            for (int r = 0; r < 4; ++r) {
                int row = rt + mt * 16 + quad * 4 + r;   // C/D: col=lane&15, row=quad*4+reg
                if (row < N_NODES) ybf[(size_t)row * 256 + n] = f2bf(acc[mt][nt][r]);
            }
        }

    __syncthreads();
    for (int b = threadIdx.x; b < NBKT; b += 256)
        if (hcnt[b]) atomicAdd(&tot[b], hcnt[b]);
}

// ---- K3: scan bucket totals -> base_, init padded cursors ----------------
__global__ __launch_bounds__(512) void scan_buckets(const int* __restrict__ tot,
                                                    int* __restrict__ base_,
                                                    int* __restrict__ cur) {
    __shared__ int s[512];
    int t = threadIdx.x;
    int v = (t < NBKT) ? tot[t] : 0;
    s[t] = v;
    __syncthreads();
    for (int o = 1; o < 512; o <<= 1) {
        int x = (t >= o) ? s[t - o] : 0;
        __syncthreads();
        s[t] += x;
        __syncthreads();
    }
    if (t < NBKT) {
        base_[t] = s[t] - v;
        cur[t * 16] = s[t] - v;    // 64 B stride: one cache line per cursor
    }
    if (t == 0) base_[NBKT] = N_EDGES;
}

// ---- K4: scatter with per-chunk LDS hist + global run claims -------------
__global__ __launch_bounds__(1024) void scatter_kernel(
        const int* __restrict__ erow, const int* __restrict__ ecol,
        const float* __restrict__ eval,
        int* __restrict__ cur, uint2* __restrict__ tmp) {
    __shared__ int cnt[NBKT];
    __shared__ int runb[NBKT];
    int t = threadIdx.x;
    if (t < NBKT) cnt[t] = 0;
    __syncthreads();
    int cb = blockIdx.x * CHUNK;
    #pragma unroll
    for (int j = 0; j < CHUNK; j += 1024) {
        int i = cb + j + t;
        if (i < N_EDGES) atomicAdd(&cnt[erow[i] >> 8], 1);
    }
    __syncthreads();
    if (t < NBKT)
        runb[t] = cnt[t] ? atomicAdd(&cur[t * 16], cnt[t]) : 0;
    __syncthreads();
    if (t < NBKT) cnt[t] = 0;        // reuse as in-run cursor
    __syncthreads();
    #pragma unroll
    for (int j = 0; j < CHUNK; j += 1024) {
        int i = cb + j + t;
        if (i < N_EDGES) {
            int r = erow[i];
            int b = r >> 8;
            int pos = runb[b] + atomicAdd(&cnt[b], 1);
            uint2 cv;
            cv.x = (unsigned)ecol[i] | ((unsigned)(r & 255) << 17);  // col < 2^17
            union { float f; unsigned u; } w; w.f = eval[i];
            cv.y = w.u;
            tmp[pos] = cv;
        }
    }
}

// ---- K5: SpMM with in-LDS per-row binning (replaces fine_sort + spmm) ----
// Block = one 256-row bucket. Phase 1: bin bucket edges by row-low into LDS.
// Phase 2: 16 half-waves each own 16 rows; half-wave gathers ybf rows
// (4-deep unroll), accumulates fp32, writes final output.
__global__ __launch_bounds__(512) void spmm_bin_kernel(
        const ushort* __restrict__ ybf,           // [N][256] bf16
        const int* __restrict__ base_,            // [NBKT+1]
        const uint2* __restrict__ tmp,            // bucket-grouped edges
        float* __restrict__ out) {                // [N][256] fp32
    __shared__ int cnt[256];
    __shared__ int rbase[256];
    __shared__ uint2 ed[CAP];                     // 72 KB
    int t = threadIdx.x;
    int b = blockIdx.x;
    int s0 = base_[b];
    int s1 = base_[b + 1];
    int nb = s1 - s0;
    int nbc = nb < CAP ? nb : CAP;

    if (t < 256) cnt[t] = 0;
    __syncthreads();
    for (int j = t; j < nbc; j += 512)
        atomicAdd(&cnt[tmp[s0 + j].x >> 17], 1);
    __syncthreads();
    int v = 0;
    if (t < 256) { v = cnt[t]; rbase[t] = v; }
    __syncthreads();
    for (int o = 1; o < 256; o <<= 1) {
        int x = 0;
        if (t >= o && t < 256) x = rbase[t - o];
        __syncthreads();
        if (t < 256) rbase[t] += x;
        __syncthreads();
    }
    if (t < 256) { rbase[t] -= v; cnt[t] = 0; }   // exclusive start; cnt = cursor
    __syncthreads();
    for (int j = t; j < nbc; j += 512) {
        uint2 cv = tmp[s0 + j];
        unsigned rl = cv.x >> 17;
        ed[rbase[rl] + atomicAdd(&cnt[rl], 1)] = cv;
    }
    __syncthreads();

    int wave = t >> 6;
    int lane = t & 63;
    int half = lane >> 5;
    int hl   = lane & 31;
    int unit = wave * 2 + half;                   // 16 units, 16 rows each
    for (int rr = 0; rr < 16; ++rr) {
        int rl  = unit * 16 + rr;
        int row = b * 256 + rl;
        if (row >= N_NODES) continue;
        int st = rbase[rl];
        int en = st + cnt[rl];
        float acc[8] = {0.f, 0.f, 0.f, 0.f, 0.f, 0.f, 0.f, 0.f};
        int e = st;
        for (; e + 3 < en; e += 4) {              // 4 gathers in flight
            uint2 c0 = ed[e], c1 = ed[e + 1], c2 = ed[e + 2], c3 = ed[e + 3];
            ushort8 y0 = *(const ushort8*)&ybf[(size_t)(c0.x & 0x1FFFF) * 256 + hl * 8];
            ushort8 y1 = *(const ushort8*)&ybf[(size_t)(c1.x & 0x1FFFF) * 256 + hl * 8];
            ushort8 y2 = *(const ushort8*)&ybf[(size_t)(c2.x & 0x1FFFF) * 256 + hl * 8];
            ushort8 y3 = *(const ushort8*)&ybf[(size_t)(c3.x & 0x1FFFF) * 256 + hl * 8];
            union { unsigned u; float f; } w0, w1, w2, w3;
            w0.u = c0.y; w1.u = c1.y; w2.u = c2.y; w3.u = c3.y;
            #pragma unroll
            for (int j = 0; j < 8; ++j) acc[j] += w0.f * bf2f(y0[j]);
            #pragma unroll
            for (int j = 0; j < 8; ++j) acc[j] += w1.f * bf2f(y1[j]);
            #pragma unroll
            for (int j = 0; j < 8; ++j) acc[j] += w2.f * bf2f(y2[j]);
            #pragma unroll
            for (int j = 0; j < 8; ++j) acc[j] += w3.f * bf2f(y3[j]);
        }
        for (; e < en; ++e) {
            uint2 c = ed[e];
            ushort8 y = *(const ushort8*)&ybf[(size_t)(c.x & 0x1FFFF) * 256 + hl * 8];
            union { unsigned u; float f; } w; w.u = c.y;
            #pragma unroll
            for (int j = 0; j < 8; ++j) acc[j] += w.f * bf2f(y[j]);
        }
        if (nb > nbc) {                           // overflow fallback (P ~ 0)
            for (int j = s0 + nbc; j < s1; ++j) {
                uint2 c = tmp[j];
                if ((int)(c.x >> 17) == rl) {
                    ushort8 y = *(const ushort8*)&ybf[(size_t)(c.x & 0x1FFFF) * 256 + hl * 8];
                    union { unsigned u; float f; } w; w.u = c.y;
                    #pragma unroll
                    for (int j2 = 0; j2 < 8; ++j2) acc[j2] += w.f * bf2f(y[j2]);
                }
            }
        }
        float4v o0 = {acc[0], acc[1], acc[2], acc[3]};
        float4v o1 = {acc[4], acc[5], acc[6], acc[7]};
        *(float4v*)&out[(size_t)row * 256 + hl * 8]     = o0;
        *(float4v*)&out[(size_t)row * 256 + hl * 8 + 4] = o1;
    }
}

// ---- launch --------------------------------------------------------------

extern "C" void kernel_launch(void* const* d_in, const int* in_sizes, int n_in,
                              void* d_out, int out_size, void* d_ws, size_t ws_size,
                              hipStream_t stream) {
    const float* x    = (const float*)d_in[0];
    const int*   erow = (const int*)d_in[1];
    const int*   ecol = (const int*)d_in[2];
    const float* eval = (const float*)d_in[3];
    const float* W    = (const float*)d_in[4];
    float* out = (float*)d_out;

    char* ws = (char*)d_ws;
    size_t off = 0;
    int* tot    = (int*)(ws + off);    off += (512 * 4);
    int* base_  = (int*)(ws + off);    off += (512 * 4);
    int* cur    = (int*)(ws + off);    off += ((size_t)NBKT * 16 * 4 + 255) & ~255ull;
    uint2* tmp  = (uint2*)(ws + off);  off += (size_t)N_EDGES * 8;
    ushort* Wbf = (ushort*)(ws + off); off += (size_t)D_FEAT * D_FEAT * 2;
    ushort* ybf = (ushort*)(ws + off); off += (size_t)N_NODES * D_FEAT * 2;

    // K1: W->bf16 + zero totals
    prep_kernel<<<257, 256, 0, stream>>>(W, Wbf, tot);
    // K2: projection y = x @ W^T (+ fused bucket histogram)
    gemm_x_kernel<<<(N_NODES + 63) / 64, 256, 0, stream>>>(x, Wbf, erow, tot, ybf);
    // K3: bucket bases + cursors
    scan_buckets<<<1, 512, 0, stream>>>(tot, base_, cur);
    // K4: bucket-grouped scatter via global run claims
    scatter_kernel<<<NBLK_E, 1024, 0, stream>>>(erow, ecol, eval, cur, tmp);
    // K5: bin-in-LDS + gather-accumulate + write final output
    spmm_bin_kernel<<<NBKT, 512, 0, stream>>>(ybf, base_, tmp, out);
}